// Round 2
// baseline (324.307 us; speedup 1.0000x reference)
//
#include <hip/hip_runtime.h>
#include <stdint.h>

#define LQ 10000
#define LK 4224
#define NQB 313          // ceil(10016/32)
#define SCALE 0.17677669529663687f

typedef __bf16 bf16x8 __attribute__((ext_vector_type(8)));
typedef float  f32x4  __attribute__((ext_vector_type(4)));

__device__ __forceinline__ unsigned short f2b(float f) {
  union { float f; unsigned u; } v; v.f = f;
  unsigned r = v.u + 0x7fffu + ((v.u >> 16) & 1u);   // RNE bf16
  return (unsigned short)(r >> 16);
}

// ---------------------------------------------------------------------------
// misc: depth-weight bias (per key) + fp32->bf16 conversion of W matrices
// grid 273 = 256 (Wconv) + 17 (bias), block 256
// ---------------------------------------------------------------------------
__global__ void misc_kernel(
    const float* __restrict__ depth, const float* __restrict__ conf,
    const float* __restrict__ dw1, const float* __restrict__ db1,
    const float* __restrict__ dw2, const float* __restrict__ db2,
    const float* __restrict__ Wq, const float* __restrict__ Wk,
    const float* __restrict__ Wv, const float* __restrict__ Wo,
    float* __restrict__ biasArr,
    unsigned short* __restrict__ Wqb, unsigned short* __restrict__ Wkb,
    unsigned short* __restrict__ Wvb, unsigned short* __restrict__ Wob) {
  int b = blockIdx.x, t = threadIdx.x;
  if (b < 256) {
    int i = b * 256 + t;            // < 65536
    int m = i >> 14, j = i & 16383;
    const float* src = (m == 0) ? Wq : (m == 1) ? Wk : (m == 2) ? Wv : Wo;
    unsigned short* dst = (m == 0) ? Wqb : (m == 1) ? Wkb : (m == 2) ? Wvb : Wob;
    dst[j] = f2b(src[j]);
    return;
  }
  int k = (b - 256) * 256 + t;
  if (k >= LK) return;
  float d = depth[k], c = conf[k];
  float t2[4];
#pragma unroll
  for (int hh = 0; hh < 4; ++hh) t2[hh] = db2[hh];
  for (int cc = 0; cc < 32; ++cc) {
    float t1 = fmaxf(fmaf(d, dw1[cc], db1[cc]), 0.f);
#pragma unroll
    for (int hh = 0; hh < 4; ++hh) t2[hh] = fmaf(t1, dw2[hh * 32 + cc], t2[hh]);
  }
  float mx = fmaxf(fmaxf(t2[0], t2[1]), fmaxf(t2[2], t2[3]));
  float e[4], s = 0.f;
#pragma unroll
  for (int hh = 0; hh < 4; ++hh) { e[hh] = __expf(t2[hh] - mx); s += e[hh]; }
  float f = 0.1f * c / s;
#pragma unroll
  for (int hh = 0; hh < 4; ++hh) biasArr[hh * LK + k] = f * e[hh];
}

// ---------------------------------------------------------------------------
// proj_q: Qb[l][dout] = sum_d query[d][l] * Wq[dout][d] + bq[dout]   (bf16 out)
// grid 157 (64-l tiles), block 256 (4 waves; wave = one 16-row M tile)
// ---------------------------------------------------------------------------
__global__ __launch_bounds__(256) void proj_q_kernel(
    const float* __restrict__ X, const unsigned short* __restrict__ Wb,
    const float* __restrict__ bias, unsigned short* __restrict__ Y) {
  __shared__ __align__(16) unsigned short Xb[64][136];
  int t = threadIdx.x;
  int l0 = blockIdx.x * 64;
#pragma unroll
  for (int i = 0; i < 32; ++i) {
    int e = t + 256 * i;
    int d = e >> 6, c = e & 63;
    int l = l0 + c;
    Xb[c][d] = f2b(l < LQ ? X[(size_t)d * LQ + l] : 0.f);
  }
  __syncthreads();
  int wv = t >> 6, lane = t & 63, lm = lane & 15, lg = lane >> 4;
  const f32x4 zf = {0.f, 0.f, 0.f, 0.f};
  bf16x8 af[4];
#pragma unroll
  for (int kk = 0; kk < 4; ++kk)
    af[kk] = *(const bf16x8*)&Xb[wv * 16 + lm][kk * 32 + lg * 8];
  f32x4 acc[8] = {zf, zf, zf, zf, zf, zf, zf, zf};
#pragma unroll
  for (int kk = 0; kk < 4; ++kk)
#pragma unroll
    for (int ni = 0; ni < 8; ++ni) {
      bf16x8 bfr = *(const bf16x8*)(Wb + (size_t)(ni * 16 + lm) * 128 + kk * 32 + lg * 8);
      acc[ni] = __builtin_amdgcn_mfma_f32_16x16x32_bf16(af[kk], bfr, acc[ni], 0, 0, 0);
    }
#pragma unroll
  for (int ni = 0; ni < 8; ++ni)
#pragma unroll
    for (int r = 0; r < 4; ++r) {
      int l = l0 + wv * 16 + lg * 4 + r;
      int dout = ni * 16 + lm;
      Y[(size_t)l * 128 + dout] = f2b(acc[ni][r] + bias[dout]);
    }
}

// ---------------------------------------------------------------------------
// proj_kv: K -> Kb (Lk,128) bf16 ; V -> Vt (128,Lk) bf16 (transposed store)
// grid (66, 2) 64-key tiles; y=0 K, y=1 V
// ---------------------------------------------------------------------------
__global__ __launch_bounds__(256) void proj_kv_kernel(
    const float* __restrict__ key, const float* __restrict__ value,
    const unsigned short* __restrict__ Wkb, const float* __restrict__ bk,
    const unsigned short* __restrict__ Wvb, const float* __restrict__ bv,
    unsigned short* __restrict__ Kb, unsigned short* __restrict__ Vt) {
  __shared__ __align__(16) unsigned short Xb[64][136];
  int t = threadIdx.x;
  int isV = blockIdx.y;
  const float* X = isV ? value : key;
  const unsigned short* Wb = isV ? Wvb : Wkb;
  const float* bb = isV ? bv : bk;
  int k0 = blockIdx.x * 64;
  int n = k0 / 704, p0 = k0 % 704;     // 64 | 704, tile never straddles a view
  const float* Xn = X + (size_t)n * 128 * 704 + p0;
#pragma unroll
  for (int i = 0; i < 32; ++i) {
    int e = t + 256 * i;
    int d = e >> 6, c = e & 63;
    Xb[c][d] = f2b(Xn[(size_t)d * 704 + c]);
  }
  __syncthreads();
  int wv = t >> 6, lane = t & 63, lm = lane & 15, lg = lane >> 4;
  const f32x4 zf = {0.f, 0.f, 0.f, 0.f};
  bf16x8 af[4];
#pragma unroll
  for (int kk = 0; kk < 4; ++kk)
    af[kk] = *(const bf16x8*)&Xb[wv * 16 + lm][kk * 32 + lg * 8];
  f32x4 acc[8] = {zf, zf, zf, zf, zf, zf, zf, zf};
#pragma unroll
  for (int kk = 0; kk < 4; ++kk)
#pragma unroll
    for (int ni = 0; ni < 8; ++ni) {
      bf16x8 bfr = *(const bf16x8*)(Wb + (size_t)(ni * 16 + lm) * 128 + kk * 32 + lg * 8);
      acc[ni] = __builtin_amdgcn_mfma_f32_16x16x32_bf16(af[kk], bfr, acc[ni], 0, 0, 0);
    }
  if (!isV) {
#pragma unroll
    for (int ni = 0; ni < 8; ++ni)
#pragma unroll
      for (int r = 0; r < 4; ++r) {
        int k = k0 + wv * 16 + lg * 4 + r;
        int dout = ni * 16 + lm;
        Kb[(size_t)k * 128 + dout] = f2b(acc[ni][r] + bb[dout]);
      }
  } else {
#pragma unroll
    for (int ni = 0; ni < 8; ++ni)
#pragma unroll
      for (int r = 0; r < 4; ++r) {
        int k = k0 + wv * 16 + lg * 4 + r;
        int dout = ni * 16 + lm;
        Vt[(size_t)dout * LK + k] = f2b(acc[ni][r] + bb[dout]);
      }
  }
}

// ---------------------------------------------------------------------------
// attn: flash attention. grid (79, 4-heads), block 256: wave w -> qblock 4*bx+w
// (all 4 waves share the same head so K/V fragment loads hit L1)
// ---------------------------------------------------------------------------
__global__ __launch_bounds__(256) void attn_kernel(
    const unsigned short* __restrict__ Qb, const unsigned short* __restrict__ Kb,
    const unsigned short* __restrict__ Vt, const float* __restrict__ biasArr,
    unsigned short* __restrict__ Ob) {
  __shared__ __align__(16) unsigned short P_lds[4][32][72];
  int t = threadIdx.x;
  int wv = t >> 6;
  int qb = blockIdx.x * 4 + wv;
  if (qb >= NQB) return;               // no barriers below: early-exit safe
  int h = blockIdx.y;
  int lane = t & 63, lm = lane & 15, lg = lane >> 4;
  const f32x4 zf = {0.f, 0.f, 0.f, 0.f};

  bf16x8 qf[2];
#pragma unroll
  for (int mi = 0; mi < 2; ++mi)
    qf[mi] = *(const bf16x8*)(Qb + (size_t)(qb * 32 + mi * 16 + lm) * 128 + h * 32 + lg * 8);

  f32x4 acc[2][2] = {{zf, zf}, {zf, zf}};
  float mrun[2][4], lrun[2][4];
#pragma unroll
  for (int mi = 0; mi < 2; ++mi)
#pragma unroll
    for (int r = 0; r < 4; ++r) { mrun[mi][r] = -1e30f; lrun[mi][r] = 0.f; }

  const float* bias_h = biasArr + h * LK;
  const unsigned short* Kh = Kb + h * 32;
  const unsigned short* Vh = Vt + (size_t)h * 32 * LK;

  for (int kb = 0; kb < 66; ++kb) {
    int k0 = kb * 64;
    bf16x8 kf[4];
#pragma unroll
    for (int ni = 0; ni < 4; ++ni)
      kf[ni] = *(const bf16x8*)(Kh + (size_t)(k0 + ni * 16 + lm) * 128 + lg * 8);
    f32x4 S[2][4];
#pragma unroll
    for (int mi = 0; mi < 2; ++mi)
#pragma unroll
      for (int ni = 0; ni < 4; ++ni)
        S[mi][ni] = __builtin_amdgcn_mfma_f32_16x16x32_bf16(qf[mi], kf[ni], zf, 0, 0, 0);
    float bvv[4];
#pragma unroll
    for (int ni = 0; ni < 4; ++ni) bvv[ni] = bias_h[k0 + ni * 16 + lm];

#pragma unroll
    for (int mi = 0; mi < 2; ++mi) {
      float sv[4][4], rmax[4], rsum[4], fac[4];
#pragma unroll
      for (int r = 0; r < 4; ++r) rmax[r] = -1e30f;
#pragma unroll
      for (int ni = 0; ni < 4; ++ni)
#pragma unroll
        for (int r = 0; r < 4; ++r) {
          float x = fmaf(S[mi][ni][r], SCALE, bvv[ni]);
          sv[ni][r] = x;
          rmax[r] = fmaxf(rmax[r], x);
        }
#pragma unroll
      for (int r = 0; r < 4; ++r) {
#pragma unroll
        for (int msk = 1; msk < 16; msk <<= 1)
          rmax[r] = fmaxf(rmax[r], __shfl_xor(rmax[r], msk));
        float mn = fmaxf(mrun[mi][r], rmax[r]);
        fac[r] = __expf(mrun[mi][r] - mn);
        mrun[mi][r] = mn;
        rsum[r] = 0.f;
      }
#pragma unroll
      for (int ni = 0; ni < 4; ++ni)
#pragma unroll
        for (int r = 0; r < 4; ++r) {
          float p = __expf(sv[ni][r] - mrun[mi][r]);
          sv[ni][r] = p;
          rsum[r] += p;
        }
#pragma unroll
      for (int r = 0; r < 4; ++r) {
#pragma unroll
        for (int msk = 1; msk < 16; msk <<= 1)
          rsum[r] += __shfl_xor(rsum[r], msk);
        lrun[mi][r] = fmaf(lrun[mi][r], fac[r], rsum[r]);
      }
#pragma unroll
      for (int nd = 0; nd < 2; ++nd)
#pragma unroll
        for (int r = 0; r < 4; ++r) acc[mi][nd][r] *= fac[r];
#pragma unroll
      for (int ni = 0; ni < 4; ++ni)
#pragma unroll
        for (int r = 0; r < 4; ++r)
          P_lds[wv][mi * 16 + lg * 4 + r][ni * 16 + lm] = f2b(sv[ni][r]);
    }
    // wave-synchronous LDS: same-wave DS ops execute in order; pin program order
    __builtin_amdgcn_sched_barrier(0);
    bf16x8 pa[2][2], vfr[2][2];
#pragma unroll
    for (int mi = 0; mi < 2; ++mi)
#pragma unroll
      for (int kk = 0; kk < 2; ++kk)
        pa[mi][kk] = *(const bf16x8*)&P_lds[wv][mi * 16 + lm][kk * 32 + lg * 8];
#pragma unroll
    for (int kk = 0; kk < 2; ++kk)
#pragma unroll
      for (int nd = 0; nd < 2; ++nd)
        vfr[kk][nd] = *(const bf16x8*)(Vh + (size_t)(nd * 16 + lm) * LK + k0 + kk * 32 + lg * 8);
#pragma unroll
    for (int mi = 0; mi < 2; ++mi)
#pragma unroll
      for (int nd = 0; nd < 2; ++nd)
#pragma unroll
        for (int kk = 0; kk < 2; ++kk)
          acc[mi][nd] = __builtin_amdgcn_mfma_f32_16x16x32_bf16(pa[mi][kk], vfr[kk][nd], acc[mi][nd], 0, 0, 0);
    __builtin_amdgcn_sched_barrier(0);
  }
#pragma unroll
  for (int mi = 0; mi < 2; ++mi)
#pragma unroll
    for (int nd = 0; nd < 2; ++nd)
#pragma unroll
      for (int r = 0; r < 4; ++r) {
        int q = qb * 32 + mi * 16 + lg * 4 + r;
        Ob[(size_t)q * 128 + h * 32 + nd * 16 + lm] = f2b(acc[mi][nd][r] / lrun[mi][r]);
      }
}

// ---------------------------------------------------------------------------
// epi: out[dout][l] = sum_d Ob[l][d]*Wo[dout][d] + bo[dout] + skip[dout][l]
// computed as C^T = Wo * Ob^T so stores are lane-coalesced along l
// grid 157 (64-l tiles), block 256 (wave = 32 dout rows)
// ---------------------------------------------------------------------------
__global__ __launch_bounds__(256) void epi_kernel(
    const unsigned short* __restrict__ Ob, const unsigned short* __restrict__ Wob,
    const float* __restrict__ bo, const float* __restrict__ skip,
    float* __restrict__ out) {
  int t = threadIdx.x, wv = t >> 6, lane = t & 63, lm = lane & 15, lg = lane >> 4;
  int l0 = blockIdx.x * 64;
  const f32x4 zf = {0.f, 0.f, 0.f, 0.f};
  bf16x8 af[2][4];
#pragma unroll
  for (int mi = 0; mi < 2; ++mi)
#pragma unroll
    for (int kk = 0; kk < 4; ++kk)
      af[mi][kk] = *(const bf16x8*)(Wob + (size_t)(wv * 32 + mi * 16 + lm) * 128 + kk * 32 + lg * 8);
  f32x4 acc[2][4] = {{zf, zf, zf, zf}, {zf, zf, zf, zf}};
#pragma unroll
  for (int kk = 0; kk < 4; ++kk) {
    bf16x8 bfr[4];
#pragma unroll
    for (int ni = 0; ni < 4; ++ni)
      bfr[ni] = *(const bf16x8*)(Ob + (size_t)(l0 + ni * 16 + lm) * 128 + kk * 32 + lg * 8);
#pragma unroll
    for (int mi = 0; mi < 2; ++mi)
#pragma unroll
      for (int ni = 0; ni < 4; ++ni)
        acc[mi][ni] = __builtin_amdgcn_mfma_f32_16x16x32_bf16(af[mi][kk], bfr[ni], acc[mi][ni], 0, 0, 0);
  }
#pragma unroll
  for (int mi = 0; mi < 2; ++mi)
#pragma unroll
    for (int r = 0; r < 4; ++r) {
      int dout = wv * 32 + mi * 16 + lg * 4 + r;
      float bb = bo[dout];
#pragma unroll
      for (int ni = 0; ni < 4; ++ni) {
        int l = l0 + ni * 16 + lm;
        if (l < LQ)
          out[(size_t)dout * LQ + l] = acc[mi][ni][r] + bb + skip[(size_t)dout * LQ + l];
      }
    }
}

// ---------------------------------------------------------------------------
extern "C" void kernel_launch(void* const* d_in, const int* in_sizes, int n_in,
                              void* d_out, int out_size, void* d_ws, size_t ws_size,
                              hipStream_t stream) {
  const float* query = (const float*)d_in[0];
  const float* key   = (const float*)d_in[1];
  const float* value = (const float*)d_in[2];
  const float* depth = (const float*)d_in[3];
  const float* conf  = (const float*)d_in[4];
  const float* skip  = (const float*)d_in[5];
  const float* Wq = (const float*)d_in[6];   const float* bq = (const float*)d_in[7];
  const float* Wk = (const float*)d_in[8];   const float* bk = (const float*)d_in[9];
  const float* Wv = (const float*)d_in[10];  const float* bv = (const float*)d_in[11];
  const float* Wo = (const float*)d_in[12];  const float* bo = (const float*)d_in[13];
  const float* dw1 = (const float*)d_in[14]; const float* db1 = (const float*)d_in[15];
  const float* dw2 = (const float*)d_in[16]; const float* db2 = (const float*)d_in[17];
  float* out = (float*)d_out;
  char* ws = (char*)d_ws;

  // workspace layout (bytes)
  unsigned short* Qb   = (unsigned short*)(ws + 0);         // 10048 x 128 bf16
  unsigned short* Kb   = (unsigned short*)(ws + 2572288);   //  4224 x 128 bf16
  unsigned short* Vt   = (unsigned short*)(ws + 3653632);   //   128 x 4224 bf16
  float*          bias = (float*)        (ws + 4734976);    //     4 x 4224 f32
  unsigned short* Wqb  = (unsigned short*)(ws + 4802560);   // 128x128 bf16 each
  unsigned short* Wkb  = (unsigned short*)(ws + 4835328);
  unsigned short* Wvb  = (unsigned short*)(ws + 4868096);
  unsigned short* Wob  = (unsigned short*)(ws + 4900864);
  unsigned short* Ob   = (unsigned short*)(ws + 4933632);   // 10048 x 128 bf16

  hipLaunchKernelGGL(misc_kernel, dim3(273), dim3(256), 0, stream,
                     depth, conf, dw1, db1, dw2, db2, Wq, Wk, Wv, Wo,
                     bias, Wqb, Wkb, Wvb, Wob);
  hipLaunchKernelGGL(proj_q_kernel, dim3(157), dim3(256), 0, stream,
                     query, Wqb, bq, Qb);
  hipLaunchKernelGGL(proj_kv_kernel, dim3(66, 2), dim3(256), 0, stream,
                     key, value, Wkb, bk, Wvb, bv, Kb, Vt);
  hipLaunchKernelGGL(attn_kernel, dim3(79, 4), dim3(256), 0, stream,
                     Qb, Kb, Vt, bias, Ob);
  hipLaunchKernelGGL(epi_kernel, dim3(157), dim3(256), 0, stream,
                     Ob, Wob, bo, skip, out);
}

// Round 5
// 276.072 us; speedup vs baseline: 1.1747x; 1.1747x over previous
//
#include <hip/hip_runtime.h>
#include <stdint.h>

#define LQ 10000
#define LK 4224
#define NQB 313          // ceil(10016/32)
#define SCALE 0.17677669529663687f

typedef __bf16 bf16x8 __attribute__((ext_vector_type(8)));
typedef float  f32x4  __attribute__((ext_vector_type(4)));
typedef unsigned short u16x4 __attribute__((ext_vector_type(4)));

__device__ __forceinline__ unsigned short f2b(float f) {
  union { float f; unsigned u; } v; v.f = f;
  unsigned r = v.u + 0x7fffu + ((v.u >> 16) & 1u);   // RNE bf16
  return (unsigned short)(r >> 16);
}

// ---------------------------------------------------------------------------
// misc: depth-weight bias (per key) + fp32->bf16 conversion of W matrices
// ---------------------------------------------------------------------------
__global__ void misc_kernel(
    const float* __restrict__ depth, const float* __restrict__ conf,
    const float* __restrict__ dw1, const float* __restrict__ db1,
    const float* __restrict__ dw2, const float* __restrict__ db2,
    const float* __restrict__ Wq, const float* __restrict__ Wk,
    const float* __restrict__ Wv, const float* __restrict__ Wo,
    float* __restrict__ biasArr,
    unsigned short* __restrict__ Wqb, unsigned short* __restrict__ Wkb,
    unsigned short* __restrict__ Wvb, unsigned short* __restrict__ Wob) {
  int b = blockIdx.x, t = threadIdx.x;
  if (b < 256) {
    int i = b * 256 + t;            // < 65536
    int m = i >> 14, j = i & 16383;
    const float* src = (m == 0) ? Wq : (m == 1) ? Wk : (m == 2) ? Wv : Wo;
    unsigned short* dst = (m == 0) ? Wqb : (m == 1) ? Wkb : (m == 2) ? Wvb : Wob;
    dst[j] = f2b(src[j]);
    return;
  }
  int k = (b - 256) * 256 + t;
  if (k >= LK) return;
  float d = depth[k], c = conf[k];
  float t2[4];
#pragma unroll
  for (int hh = 0; hh < 4; ++hh) t2[hh] = db2[hh];
  for (int cc = 0; cc < 32; ++cc) {
    float t1 = fmaxf(fmaf(d, dw1[cc], db1[cc]), 0.f);
#pragma unroll
    for (int hh = 0; hh < 4; ++hh) t2[hh] = fmaf(t1, dw2[hh * 32 + cc], t2[hh]);
  }
  float mx = fmaxf(fmaxf(t2[0], t2[1]), fmaxf(t2[2], t2[3]));
  float e[4], s = 0.f;
#pragma unroll
  for (int hh = 0; hh < 4; ++hh) { e[hh] = __expf(t2[hh] - mx); s += e[hh]; }
  float f = 0.1f * c / s;
#pragma unroll
  for (int hh = 0; hh < 4; ++hh) biasArr[hh * LK + k] = f * e[hh];
}

// ---------------------------------------------------------------------------
// proj_q: Qb[l][dout] = sum_d query[d][l] * Wq[dout][d] + bq[dout]   (bf16 out)
// ---------------------------------------------------------------------------
__global__ __launch_bounds__(256) void proj_q_kernel(
    const float* __restrict__ X, const unsigned short* __restrict__ Wb,
    const float* __restrict__ bias, unsigned short* __restrict__ Y) {
  __shared__ __align__(16) unsigned short Xb[64][136];
  int t = threadIdx.x;
  int l0 = blockIdx.x * 64;
#pragma unroll
  for (int i = 0; i < 32; ++i) {
    int e = t + 256 * i;
    int d = e >> 6, c = e & 63;
    int l = l0 + c;
    Xb[c][d] = f2b(l < LQ ? X[(size_t)d * LQ + l] : 0.f);
  }
  __syncthreads();
  int wv = t >> 6, lane = t & 63, lm = lane & 15, lg = lane >> 4;
  const f32x4 zf = {0.f, 0.f, 0.f, 0.f};
  bf16x8 af[4];
#pragma unroll
  for (int kk = 0; kk < 4; ++kk)
    af[kk] = *(const bf16x8*)&Xb[wv * 16 + lm][kk * 32 + lg * 8];
  f32x4 acc[8] = {zf, zf, zf, zf, zf, zf, zf, zf};
#pragma unroll
  for (int kk = 0; kk < 4; ++kk)
#pragma unroll
    for (int ni = 0; ni < 8; ++ni) {
      bf16x8 bfr = *(const bf16x8*)(Wb + (size_t)(ni * 16 + lm) * 128 + kk * 32 + lg * 8);
      acc[ni] = __builtin_amdgcn_mfma_f32_16x16x32_bf16(af[kk], bfr, acc[ni], 0, 0, 0);
    }
#pragma unroll
  for (int ni = 0; ni < 8; ++ni)
#pragma unroll
    for (int r = 0; r < 4; ++r) {
      int l = l0 + wv * 16 + lg * 4 + r;
      int dout = ni * 16 + lm;
      Y[(size_t)l * 128 + dout] = f2b(acc[ni][r] + bias[dout]);
    }
}

// ---------------------------------------------------------------------------
// proj_kv: K -> Kb (Lk,128) bf16 ; V -> Vt (128,Lk) bf16 (transposed store)
// ---------------------------------------------------------------------------
__global__ __launch_bounds__(256) void proj_kv_kernel(
    const float* __restrict__ key, const float* __restrict__ value,
    const unsigned short* __restrict__ Wkb, const float* __restrict__ bk,
    const unsigned short* __restrict__ Wvb, const float* __restrict__ bv,
    unsigned short* __restrict__ Kb, unsigned short* __restrict__ Vt) {
  __shared__ __align__(16) unsigned short Xb[64][136];
  int t = threadIdx.x;
  int isV = blockIdx.y;
  const float* X = isV ? value : key;
  const unsigned short* Wb = isV ? Wvb : Wkb;
  const float* bb = isV ? bv : bk;
  int k0 = blockIdx.x * 64;
  int n = k0 / 704, p0 = k0 % 704;     // 64 | 704, tile never straddles a view
  const float* Xn = X + (size_t)n * 128 * 704 + p0;
#pragma unroll
  for (int i = 0; i < 32; ++i) {
    int e = t + 256 * i;
    int d = e >> 6, c = e & 63;
    Xb[c][d] = f2b(Xn[(size_t)d * 704 + c]);
  }
  __syncthreads();
  int wv = t >> 6, lane = t & 63, lm = lane & 15, lg = lane >> 4;
  const f32x4 zf = {0.f, 0.f, 0.f, 0.f};
  bf16x8 af[4];
#pragma unroll
  for (int kk = 0; kk < 4; ++kk)
    af[kk] = *(const bf16x8*)&Xb[wv * 16 + lm][kk * 32 + lg * 8];
  f32x4 acc[8] = {zf, zf, zf, zf, zf, zf, zf, zf};
#pragma unroll
  for (int kk = 0; kk < 4; ++kk)
#pragma unroll
    for (int ni = 0; ni < 8; ++ni) {
      bf16x8 bfr = *(const bf16x8*)(Wb + (size_t)(ni * 16 + lm) * 128 + kk * 32 + lg * 8);
      acc[ni] = __builtin_amdgcn_mfma_f32_16x16x32_bf16(af[kk], bfr, acc[ni], 0, 0, 0);
    }
  if (!isV) {
#pragma unroll
    for (int ni = 0; ni < 8; ++ni)
#pragma unroll
      for (int r = 0; r < 4; ++r) {
        int k = k0 + wv * 16 + lg * 4 + r;
        int dout = ni * 16 + lm;
        Kb[(size_t)k * 128 + dout] = f2b(acc[ni][r] + bb[dout]);
      }
  } else {
#pragma unroll
    for (int ni = 0; ni < 8; ++ni)
#pragma unroll
      for (int r = 0; r < 4; ++r) {
        int k = k0 + wv * 16 + lg * 4 + r;
        int dout = ni * 16 + lm;
        Vt[(size_t)dout * LK + k] = f2b(acc[ni][r] + bb[dout]);
      }
  }
}

// ---------------------------------------------------------------------------
// attn_part: split-K flash attention partial. grid (79, 4-heads, C-chunks),
// block 256: wave wv -> qblock 4*bx+wv; chunk = bz covers tiles [bz*tpc, +tpc)
// Writes unnormalized O (fp32), running max m and denom l per q row.
// ---------------------------------------------------------------------------
__global__ __launch_bounds__(256) void attn_part_kernel(
    const unsigned short* __restrict__ Qb, const unsigned short* __restrict__ Kb,
    const unsigned short* __restrict__ Vt, const float* __restrict__ biasArr,
    float* __restrict__ Opart, float* __restrict__ Ml, int tpc, int C) {
  __shared__ __align__(16) unsigned short P_lds[4][32][72];
  int t = threadIdx.x;
  int wv = t >> 6;
  int qb = blockIdx.x * 4 + wv;
  if (qb >= NQB) return;               // no barriers below: early-exit safe
  int h = blockIdx.y, c = blockIdx.z;
  int lane = t & 63, lm = lane & 15, lg = lane >> 4;
  const f32x4 zf = {0.f, 0.f, 0.f, 0.f};

  bf16x8 qf[2];
#pragma unroll
  for (int mi = 0; mi < 2; ++mi)
    qf[mi] = *(const bf16x8*)(Qb + (size_t)(qb * 32 + mi * 16 + lm) * 128 + h * 32 + lg * 8);

  f32x4 acc[2][2] = {{zf, zf}, {zf, zf}};
  float mrun[2][4], lrun[2][4];
#pragma unroll
  for (int mi = 0; mi < 2; ++mi)
#pragma unroll
    for (int r = 0; r < 4; ++r) { mrun[mi][r] = -1e30f; lrun[mi][r] = 0.f; }

  const float* bias_h = biasArr + h * LK;
  const unsigned short* Kh = Kb + h * 32;
  const unsigned short* Vh = Vt + (size_t)h * 32 * LK;

  int kb_end = c * tpc + tpc;
  for (int kb = c * tpc; kb < kb_end; ++kb) {
    int k0 = kb * 64;
    bf16x8 kf[4];
#pragma unroll
    for (int ni = 0; ni < 4; ++ni)
      kf[ni] = *(const bf16x8*)(Kh + (size_t)(k0 + ni * 16 + lm) * 128 + lg * 8);
    f32x4 S[2][4];
#pragma unroll
    for (int mi = 0; mi < 2; ++mi)
#pragma unroll
      for (int ni = 0; ni < 4; ++ni)
        S[mi][ni] = __builtin_amdgcn_mfma_f32_16x16x32_bf16(qf[mi], kf[ni], zf, 0, 0, 0);
    float bvv[4];
#pragma unroll
    for (int ni = 0; ni < 4; ++ni) bvv[ni] = bias_h[k0 + ni * 16 + lm];

#pragma unroll
    for (int mi = 0; mi < 2; ++mi) {
      float sv[4][4], rmax[4], rsum[4], fac[4];
#pragma unroll
      for (int r = 0; r < 4; ++r) rmax[r] = -1e30f;
#pragma unroll
      for (int ni = 0; ni < 4; ++ni)
#pragma unroll
        for (int r = 0; r < 4; ++r) {
          float x = fmaf(S[mi][ni][r], SCALE, bvv[ni]);
          sv[ni][r] = x;
          rmax[r] = fmaxf(rmax[r], x);
        }
#pragma unroll
      for (int r = 0; r < 4; ++r) {
#pragma unroll
        for (int msk = 1; msk < 16; msk <<= 1)
          rmax[r] = fmaxf(rmax[r], __shfl_xor(rmax[r], msk));
        float mn = fmaxf(mrun[mi][r], rmax[r]);
        fac[r] = __expf(mrun[mi][r] - mn);
        mrun[mi][r] = mn;
        rsum[r] = 0.f;
      }
#pragma unroll
      for (int ni = 0; ni < 4; ++ni)
#pragma unroll
        for (int r = 0; r < 4; ++r) {
          float p = __expf(sv[ni][r] - mrun[mi][r]);
          sv[ni][r] = p;
          rsum[r] += p;
        }
#pragma unroll
      for (int r = 0; r < 4; ++r) {
#pragma unroll
        for (int msk = 1; msk < 16; msk <<= 1)
          rsum[r] += __shfl_xor(rsum[r], msk);
        lrun[mi][r] = fmaf(lrun[mi][r], fac[r], rsum[r]);
      }
#pragma unroll
      for (int nd = 0; nd < 2; ++nd)
#pragma unroll
        for (int r = 0; r < 4; ++r) acc[mi][nd][r] *= fac[r];
#pragma unroll
      for (int ni = 0; ni < 4; ++ni)
#pragma unroll
        for (int r = 0; r < 4; ++r)
          P_lds[wv][mi * 16 + lg * 4 + r][ni * 16 + lm] = f2b(sv[ni][r]);
    }
    // wave-synchronous LDS: same-wave DS ops execute in order; pin program order
    __builtin_amdgcn_sched_barrier(0);
    bf16x8 pa[2][2], vfr[2][2];
#pragma unroll
    for (int mi = 0; mi < 2; ++mi)
#pragma unroll
      for (int kk = 0; kk < 2; ++kk)
        pa[mi][kk] = *(const bf16x8*)&P_lds[wv][mi * 16 + lm][kk * 32 + lg * 8];
#pragma unroll
    for (int kk = 0; kk < 2; ++kk)
#pragma unroll
      for (int nd = 0; nd < 2; ++nd)
        vfr[kk][nd] = *(const bf16x8*)(Vh + (size_t)(nd * 16 + lm) * LK + k0 + kk * 32 + lg * 8);
#pragma unroll
    for (int mi = 0; mi < 2; ++mi)
#pragma unroll
      for (int nd = 0; nd < 2; ++nd)
#pragma unroll
        for (int kk = 0; kk < 2; ++kk)
          acc[mi][nd] = __builtin_amdgcn_mfma_f32_16x16x32_bf16(pa[mi][kk], vfr[kk][nd], acc[mi][nd], 0, 0, 0);
    __builtin_amdgcn_sched_barrier(0);
  }
  size_t pbase = (size_t)(qb * 4 + h) * C + c;
  float* Op = Opart + pbase * 1024;
#pragma unroll
  for (int mi = 0; mi < 2; ++mi)
#pragma unroll
    for (int nd = 0; nd < 2; ++nd)
#pragma unroll
      for (int r = 0; r < 4; ++r)
        Op[(mi * 16 + lg * 4 + r) * 32 + nd * 16 + lm] = acc[mi][nd][r];
  if (lm == 0) {
    float* MlB = Ml + pbase * 64;
#pragma unroll
    for (int mi = 0; mi < 2; ++mi)
#pragma unroll
      for (int r = 0; r < 4; ++r) {
        MlB[mi * 16 + lg * 4 + r] = mrun[mi][r];
        MlB[32 + mi * 16 + lg * 4 + r] = lrun[mi][r];
      }
  }
}

// ---------------------------------------------------------------------------
// combine: merge C partials per (qb, h) -> Ob bf16.  grid (79, 4), block 256.
// ---------------------------------------------------------------------------
__global__ __launch_bounds__(256) void combine_kernel(
    const float* __restrict__ Opart, const float* __restrict__ Ml,
    unsigned short* __restrict__ Ob, int C) {
  __shared__ float wls[4][7][32];   // [wave][c -> w_c][q]; [wave][6][q] = 1/l_tot
  int t = threadIdx.x, wv = t >> 6, lane = t & 63;
  int qb = blockIdx.x * 4 + wv;
  if (qb >= NQB) return;            // per-wave LDS region, no barriers: safe
  int h = blockIdx.y;
  size_t base = (size_t)(qb * 4 + h) * C;
  if (lane < 32) {
    float M = -1e30f;
    for (int c = 0; c < C; ++c)
      M = fmaxf(M, Ml[(base + c) * 64 + lane]);
    float lt = 0.f;
    for (int c = 0; c < C; ++c) {
      float w = __expf(Ml[(base + c) * 64 + lane] - M);
      wls[wv][c][lane] = w;
      lt += Ml[(base + c) * 64 + 32 + lane] * w;
    }
    wls[wv][6][lane] = 1.f / lt;
  }
  __builtin_amdgcn_sched_barrier(0);   // same-wave DS ordering covers lanes 32..63
  const float* Op = Opart + base * 1024;
#pragma unroll
  for (int j = 0; j < 4; ++j) {
    int q = j * 8 + (lane >> 3);
    int d = (lane & 7) * 4;
    f32x4 accv = {0.f, 0.f, 0.f, 0.f};
    for (int c = 0; c < C; ++c) {
      f32x4 v = *(const f32x4*)(Op + c * 1024 + j * 256 + lane * 4);
      float w = wls[wv][c][q];
#pragma unroll
      for (int i = 0; i < 4; ++i) accv[i] = fmaf(v[i], w, accv[i]);
    }
    float linv = wls[wv][6][q];
    u16x4 o4;
#pragma unroll
    for (int i = 0; i < 4; ++i) o4[i] = f2b(accv[i] * linv);
    *(u16x4*)(Ob + (size_t)(qb * 32 + q) * 128 + h * 32 + d) = o4;
  }
}

// ---------------------------------------------------------------------------
// epi: out[dout][l] = sum_d Ob[l][d]*Wo[dout][d] + bo[dout] + skip[dout][l]
// ---------------------------------------------------------------------------
__global__ __launch_bounds__(256) void epi_kernel(
    const unsigned short* __restrict__ Ob, const unsigned short* __restrict__ Wob,
    const float* __restrict__ bo, const float* __restrict__ skip,
    float* __restrict__ out) {
  int t = threadIdx.x, wv = t >> 6, lane = t & 63, lm = lane & 15, lg = lane >> 4;
  int l0 = blockIdx.x * 64;
  const f32x4 zf = {0.f, 0.f, 0.f, 0.f};
  bf16x8 af[2][4];
#pragma unroll
  for (int mi = 0; mi < 2; ++mi)
#pragma unroll
    for (int kk = 0; kk < 4; ++kk)
      af[mi][kk] = *(const bf16x8*)(Wob + (size_t)(wv * 32 + mi * 16 + lm) * 128 + kk * 32 + lg * 8);
  f32x4 acc[2][4] = {{zf, zf, zf, zf}, {zf, zf, zf, zf}};
#pragma unroll
  for (int kk = 0; kk < 4; ++kk) {
    bf16x8 bfr[4];
#pragma unroll
    for (int ni = 0; ni < 4; ++ni)
      bfr[ni] = *(const bf16x8*)(Ob + (size_t)(l0 + ni * 16 + lm) * 128 + kk * 32 + lg * 8);
#pragma unroll
    for (int mi = 0; mi < 2; ++mi)
#pragma unroll
      for (int ni = 0; ni < 4; ++ni)
        acc[mi][ni] = __builtin_amdgcn_mfma_f32_16x16x32_bf16(af[mi][kk], bfr[ni], acc[mi][ni], 0, 0, 0);
  }
#pragma unroll
  for (int mi = 0; mi < 2; ++mi)
#pragma unroll
    for (int r = 0; r < 4; ++r) {
      int dout = wv * 32 + mi * 16 + lg * 4 + r;
      float bb = bo[dout];
#pragma unroll
      for (int ni = 0; ni < 4; ++ni) {
        int l = l0 + ni * 16 + lm;
        if (l < LQ)
          out[(size_t)dout * LQ + l] = acc[mi][ni][r] + bb + skip[(size_t)dout * LQ + l];
      }
    }
}

// ---------------------------------------------------------------------------
extern "C" void kernel_launch(void* const* d_in, const int* in_sizes, int n_in,
                              void* d_out, int out_size, void* d_ws, size_t ws_size,
                              hipStream_t stream) {
  const float* query = (const float*)d_in[0];
  const float* key   = (const float*)d_in[1];
  const float* value = (const float*)d_in[2];
  const float* depth = (const float*)d_in[3];
  const float* conf  = (const float*)d_in[4];
  const float* skip  = (const float*)d_in[5];
  const float* Wq = (const float*)d_in[6];   const float* bq = (const float*)d_in[7];
  const float* Wk = (const float*)d_in[8];   const float* bk = (const float*)d_in[9];
  const float* Wv = (const float*)d_in[10];  const float* bv = (const float*)d_in[11];
  const float* Wo = (const float*)d_in[12];  const float* bo = (const float*)d_in[13];
  const float* dw1 = (const float*)d_in[14]; const float* db1 = (const float*)d_in[15];
  const float* dw2 = (const float*)d_in[16]; const float* db2 = (const float*)d_in[17];
  float* out = (float*)d_out;
  char* ws = (char*)d_ws;

  // workspace layout (bytes)
  unsigned short* Qb   = (unsigned short*)(ws + 0);         // 10048 x 128 bf16
  unsigned short* Kb   = (unsigned short*)(ws + 2572288);   //  4224 x 128 bf16
  unsigned short* Vt   = (unsigned short*)(ws + 3653632);   //   128 x 4224 bf16
  float*          bias = (float*)        (ws + 4734976);    //     4 x 4224 f32
  unsigned short* Wqb  = (unsigned short*)(ws + 4802560);   // 128x128 bf16 each
  unsigned short* Wkb  = (unsigned short*)(ws + 4835328);
  unsigned short* Wvb  = (unsigned short*)(ws + 4868096);
  unsigned short* Wob  = (unsigned short*)(ws + 4900864);
  unsigned short* Ob   = (unsigned short*)(ws + 4933632);   // 10048 x 128 bf16
  const size_t splitOff = 7505920;                          // after Ob

  // pick largest chunk count C (divides 66) whose partials fit in ws
  int C = 1;
  {
    const int cand[4] = {6, 3, 2, 1};
    for (int i = 0; i < 4; ++i) {
      size_t need = splitOff + (size_t)NQB * 4 * cand[i] * (4096 + 256);
      if (ws_size >= need) { C = cand[i]; break; }
    }
  }
  int tpc = 66 / C;
  float* Opart = (float*)(ws + splitOff);
  float* Ml    = (float*)(ws + splitOff + (size_t)NQB * 4 * C * 4096);

  hipLaunchKernelGGL(misc_kernel, dim3(273), dim3(256), 0, stream,
                     depth, conf, dw1, db1, dw2, db2, Wq, Wk, Wv, Wo,
                     bias, Wqb, Wkb, Wvb, Wob);
  hipLaunchKernelGGL(proj_q_kernel, dim3(157), dim3(256), 0, stream,
                     query, Wqb, bq, Qb);
  hipLaunchKernelGGL(proj_kv_kernel, dim3(66, 2), dim3(256), 0, stream,
                     key, value, Wkb, bk, Wvb, bv, Kb, Vt);
  hipLaunchKernelGGL(attn_part_kernel, dim3(79, 4, C), dim3(256), 0, stream,
                     Qb, Kb, Vt, bias, Opart, Ml, tpc, C);
  hipLaunchKernelGGL(combine_kernel, dim3(79, 4), dim3(256), 0, stream,
                     Opart, Ml, Ob, C);
  hipLaunchKernelGGL(epi_kernel, dim3(157), dim3(256), 0, stream,
                     Ob, Wob, bo, skip, out);
}

// Round 9
// 260.943 us; speedup vs baseline: 1.2428x; 1.0580x over previous
//
#include <hip/hip_runtime.h>
#include <stdint.h>

#define LQ 10000
#define LK 4224
#define NQB 313          // ceil(10016/32)
#define SCALE 0.17677669529663687f

typedef __bf16 bf16x8 __attribute__((ext_vector_type(8)));
typedef __bf16 bf16x4 __attribute__((ext_vector_type(4)));
typedef float  f32x4  __attribute__((ext_vector_type(4)));
typedef unsigned short u16x4 __attribute__((ext_vector_type(4)));

__device__ __forceinline__ unsigned short f2b(float f) {
  union { float f; unsigned u; } v; v.f = f;
  unsigned r = v.u + 0x7fffu + ((v.u >> 16) & 1u);   // RNE bf16
  return (unsigned short)(r >> 16);
}

// ---------------------------------------------------------------------------
// misc: depth-weight bias (per key) + fp32->bf16 conversion of W matrices
// ---------------------------------------------------------------------------
__global__ void misc_kernel(
    const float* __restrict__ depth, const float* __restrict__ conf,
    const float* __restrict__ dw1, const float* __restrict__ db1,
    const float* __restrict__ dw2, const float* __restrict__ db2,
    const float* __restrict__ Wq, const float* __restrict__ Wk,
    const float* __restrict__ Wv, const float* __restrict__ Wo,
    float* __restrict__ biasArr,
    unsigned short* __restrict__ Wqb, unsigned short* __restrict__ Wkb,
    unsigned short* __restrict__ Wvb, unsigned short* __restrict__ Wob) {
  int b = blockIdx.x, t = threadIdx.x;
  if (b < 256) {
    int i = b * 256 + t;            // < 65536
    int m = i >> 14, j = i & 16383;
    const float* src = (m == 0) ? Wq : (m == 1) ? Wk : (m == 2) ? Wv : Wo;
    unsigned short* dst = (m == 0) ? Wqb : (m == 1) ? Wkb : (m == 2) ? Wvb : Wob;
    dst[j] = f2b(src[j]);
    return;
  }
  int k = (b - 256) * 256 + t;
  if (k >= LK) return;
  float d = depth[k], c = conf[k];
  float t2[4];
#pragma unroll
  for (int hh = 0; hh < 4; ++hh) t2[hh] = db2[hh];
  for (int cc = 0; cc < 32; ++cc) {
    float t1 = fmaxf(fmaf(d, dw1[cc], db1[cc]), 0.f);
#pragma unroll
    for (int hh = 0; hh < 4; ++hh) t2[hh] = fmaf(t1, dw2[hh * 32 + cc], t2[hh]);
  }
  float mx = fmaxf(fmaxf(t2[0], t2[1]), fmaxf(t2[2], t2[3]));
  float e[4], s = 0.f;
#pragma unroll
  for (int hh = 0; hh < 4; ++hh) { e[hh] = __expf(t2[hh] - mx); s += e[hh]; }
  float f = 0.1f * c / s;
#pragma unroll
  for (int hh = 0; hh < 4; ++hh) biasArr[hh * LK + k] = f * e[hh];
}

// ---------------------------------------------------------------------------
// proj_q: Qb[l][dout] = sum_d query[d][l] * Wq[dout][d] + bq[dout]   (bf16 out)
// ---------------------------------------------------------------------------
__global__ __launch_bounds__(256) void proj_q_kernel(
    const float* __restrict__ X, const unsigned short* __restrict__ Wb,
    const float* __restrict__ bias, unsigned short* __restrict__ Y) {
  __shared__ __align__(16) unsigned short Xb[64][136];
  int t = threadIdx.x;
  int l0 = blockIdx.x * 64;
#pragma unroll
  for (int i = 0; i < 32; ++i) {
    int e = t + 256 * i;
    int d = e >> 6, c = e & 63;
    int l = l0 + c;
    Xb[c][d] = f2b(l < LQ ? X[(size_t)d * LQ + l] : 0.f);
  }
  __syncthreads();
  int wv = t >> 6, lane = t & 63, lm = lane & 15, lg = lane >> 4;
  const f32x4 zf = {0.f, 0.f, 0.f, 0.f};
  bf16x8 af[4];
#pragma unroll
  for (int kk = 0; kk < 4; ++kk)
    af[kk] = *(const bf16x8*)&Xb[wv * 16 + lm][kk * 32 + lg * 8];
  f32x4 acc[8] = {zf, zf, zf, zf, zf, zf, zf, zf};
#pragma unroll
  for (int kk = 0; kk < 4; ++kk)
#pragma unroll
    for (int ni = 0; ni < 8; ++ni) {
      bf16x8 bfr = *(const bf16x8*)(Wb + (size_t)(ni * 16 + lm) * 128 + kk * 32 + lg * 8);
      acc[ni] = __builtin_amdgcn_mfma_f32_16x16x32_bf16(af[kk], bfr, acc[ni], 0, 0, 0);
    }
#pragma unroll
  for (int ni = 0; ni < 8; ++ni)
#pragma unroll
    for (int r = 0; r < 4; ++r) {
      int l = l0 + wv * 16 + lg * 4 + r;
      int dout = ni * 16 + lm;
      Y[(size_t)l * 128 + dout] = f2b(acc[ni][r] + bias[dout]);
    }
}

// ---------------------------------------------------------------------------
// proj_kv: K -> Kb (Lk,128) bf16 ; V -> Vt (128,Lk) bf16 (transposed store)
// ---------------------------------------------------------------------------
__global__ __launch_bounds__(256) void proj_kv_kernel(
    const float* __restrict__ key, const float* __restrict__ value,
    const unsigned short* __restrict__ Wkb, const float* __restrict__ bk,
    const unsigned short* __restrict__ Wvb, const float* __restrict__ bv,
    unsigned short* __restrict__ Kb, unsigned short* __restrict__ Vt) {
  __shared__ __align__(16) unsigned short Xb[64][136];
  int t = threadIdx.x;
  int isV = blockIdx.y;
  const float* X = isV ? value : key;
  const unsigned short* Wb = isV ? Wvb : Wkb;
  const float* bb = isV ? bv : bk;
  int k0 = blockIdx.x * 64;
  int n = k0 / 704, p0 = k0 % 704;     // 64 | 704, tile never straddles a view
  const float* Xn = X + (size_t)n * 128 * 704 + p0;
#pragma unroll
  for (int i = 0; i < 32; ++i) {
    int e = t + 256 * i;
    int d = e >> 6, c = e & 63;
    Xb[c][d] = f2b(Xn[(size_t)d * 704 + c]);
  }
  __syncthreads();
  int wv = t >> 6, lane = t & 63, lm = lane & 15, lg = lane >> 4;
  const f32x4 zf = {0.f, 0.f, 0.f, 0.f};
  bf16x8 af[4];
#pragma unroll
  for (int kk = 0; kk < 4; ++kk)
    af[kk] = *(const bf16x8*)&Xb[wv * 16 + lm][kk * 32 + lg * 8];
  f32x4 acc[8] = {zf, zf, zf, zf, zf, zf, zf, zf};
#pragma unroll
  for (int kk = 0; kk < 4; ++kk)
#pragma unroll
    for (int ni = 0; ni < 8; ++ni) {
      bf16x8 bfr = *(const bf16x8*)(Wb + (size_t)(ni * 16 + lm) * 128 + kk * 32 + lg * 8);
      acc[ni] = __builtin_amdgcn_mfma_f32_16x16x32_bf16(af[kk], bfr, acc[ni], 0, 0, 0);
    }
  if (!isV) {
#pragma unroll
    for (int ni = 0; ni < 8; ++ni)
#pragma unroll
      for (int r = 0; r < 4; ++r) {
        int k = k0 + wv * 16 + lg * 4 + r;
        int dout = ni * 16 + lm;
        Kb[(size_t)k * 128 + dout] = f2b(acc[ni][r] + bb[dout]);
      }
  } else {
#pragma unroll
    for (int ni = 0; ni < 8; ++ni)
#pragma unroll
      for (int r = 0; r < 4; ++r) {
        int k = k0 + wv * 16 + lg * 4 + r;
        int dout = ni * 16 + lm;
        Vt[(size_t)dout * LK + k] = f2b(acc[ni][r] + bb[dout]);
      }
  }
}

// ---------------------------------------------------------------------------
// attn_part: split-K flash attention partial, SWAPPED QK^T (S^T = mfma(K,Q)):
// lane owns query q=lane&15 (per mi tile) and 16 keys (lg*4+r per ni tile)
// -> row softmax is 15 in-reg ops + 2 shuffles. grid (79, 4, C), block 256.
// ---------------------------------------------------------------------------
__global__ __launch_bounds__(256) void attn_part_kernel(
    const unsigned short* __restrict__ Qb, const unsigned short* __restrict__ Kb,
    const unsigned short* __restrict__ Vt, const float* __restrict__ biasArr,
    float* __restrict__ Opart, float* __restrict__ Ml, int tpc, int C) {
  __shared__ __align__(16) unsigned short P_lds[4][32][72];
  int t = threadIdx.x;
  int wv = t >> 6;
  int qb = blockIdx.x * 4 + wv;
  if (qb >= NQB) return;               // no barriers below: early-exit safe
  int h = blockIdx.y, c = blockIdx.z;
  int lane = t & 63, lm = lane & 15, lg = lane >> 4;
  const f32x4 zf = {0.f, 0.f, 0.f, 0.f};

  bf16x8 qf[2];
#pragma unroll
  for (int mi = 0; mi < 2; ++mi)
    qf[mi] = *(const bf16x8*)(Qb + (size_t)(qb * 32 + mi * 16 + lm) * 128 + h * 32 + lg * 8);

  f32x4 acc[2][2] = {{zf, zf}, {zf, zf}};
  float mrun[2] = {-1e30f, -1e30f}, lrun[2] = {0.f, 0.f};

  const float* bias_h = biasArr + h * LK;
  const unsigned short* Kh = Kb + h * 32;
  const unsigned short* Vh = Vt + (size_t)h * 32 * LK;

  int kb_end = c * tpc + tpc;
  for (int kb = c * tpc; kb < kb_end; ++kb) {
    int k0 = kb * 64;
    bf16x8 kf[4];
#pragma unroll
    for (int ni = 0; ni < 4; ++ni)
      kf[ni] = *(const bf16x8*)(Kh + (size_t)(k0 + ni * 16 + lm) * 128 + lg * 8);
    // S^T[key][query]: A = K-frag, B = Q-frag
    f32x4 S[2][4];
#pragma unroll
    for (int mi = 0; mi < 2; ++mi)
#pragma unroll
      for (int ni = 0; ni < 4; ++ni)
        S[mi][ni] = __builtin_amdgcn_mfma_f32_16x16x32_bf16(kf[ni], qf[mi], zf, 0, 0, 0);
    // bias per key: key = k0 + ni*16 + lg*4 + r  -> coalesced f32x4
    f32x4 bvv[4];
#pragma unroll
    for (int ni = 0; ni < 4; ++ni)
      bvv[ni] = *(const f32x4*)(bias_h + k0 + ni * 16 + lg * 4);

#pragma unroll
    for (int mi = 0; mi < 2; ++mi) {
      float pmax = -1e30f;
#pragma unroll
      for (int ni = 0; ni < 4; ++ni)
#pragma unroll
        for (int r = 0; r < 4; ++r) {
          float x = fmaf(S[mi][ni][r], SCALE, bvv[ni][r]);
          S[mi][ni][r] = x;
          pmax = fmaxf(pmax, x);
        }
      pmax = fmaxf(pmax, __shfl_xor(pmax, 16));
      pmax = fmaxf(pmax, __shfl_xor(pmax, 32));
      float mn = fmaxf(mrun[mi], pmax);
      float fac = __expf(mrun[mi] - mn);
      mrun[mi] = mn;
      float psum = 0.f;
#pragma unroll
      for (int ni = 0; ni < 4; ++ni) {
        bf16x4 pk;
#pragma unroll
        for (int r = 0; r < 4; ++r) {
          float p = __expf(S[mi][ni][r] - mn);
          psum += p;
          pk[r] = (__bf16)p;
        }
        *(bf16x4*)&P_lds[wv][mi * 16 + lm][ni * 16 + lg * 4] = pk;
      }
      psum += __shfl_xor(psum, 16);
      psum += __shfl_xor(psum, 32);
      lrun[mi] = fmaf(lrun[mi], fac, psum);
      // transpose fac (per q=lm) into acc layout (q = lg*4+r)
      float fac_t[4];
#pragma unroll
      for (int r = 0; r < 4; ++r) fac_t[r] = __shfl(fac, lg * 4 + r);
#pragma unroll
      for (int nd = 0; nd < 2; ++nd)
#pragma unroll
        for (int r = 0; r < 4; ++r) acc[mi][nd][r] *= fac_t[r];
    }
    // wave-synchronous LDS: same-wave DS ops execute in order; pin program order
    asm volatile("" ::: "memory");
    __builtin_amdgcn_sched_barrier(0);
    bf16x8 pa[2][2], vfr[2][2];
#pragma unroll
    for (int mi = 0; mi < 2; ++mi)
#pragma unroll
      for (int kk = 0; kk < 2; ++kk)
        pa[mi][kk] = *(const bf16x8*)&P_lds[wv][mi * 16 + lm][kk * 32 + lg * 8];
#pragma unroll
    for (int kk = 0; kk < 2; ++kk)
#pragma unroll
      for (int nd = 0; nd < 2; ++nd)
        vfr[kk][nd] = *(const bf16x8*)(Vh + (size_t)(nd * 16 + lm) * LK + k0 + kk * 32 + lg * 8);
#pragma unroll
    for (int mi = 0; mi < 2; ++mi)
#pragma unroll
      for (int nd = 0; nd < 2; ++nd)
#pragma unroll
        for (int kk = 0; kk < 2; ++kk)
          acc[mi][nd] = __builtin_amdgcn_mfma_f32_16x16x32_bf16(pa[mi][kk], vfr[kk][nd], acc[mi][nd], 0, 0, 0);
    asm volatile("" ::: "memory");
    __builtin_amdgcn_sched_barrier(0);
  }
  size_t pbase = (size_t)(qb * 4 + h) * C + c;
  float* Op = Opart + pbase * 1024;
#pragma unroll
  for (int mi = 0; mi < 2; ++mi)
#pragma unroll
    for (int nd = 0; nd < 2; ++nd)
#pragma unroll
      for (int r = 0; r < 4; ++r)
        Op[(mi * 16 + lg * 4 + r) * 32 + nd * 16 + lm] = acc[mi][nd][r];
  if (lane < 16) {
    float* MlB = Ml + pbase * 64;
#pragma unroll
    for (int mi = 0; mi < 2; ++mi) {
      MlB[mi * 16 + lm] = mrun[mi];
      MlB[32 + mi * 16 + lm] = lrun[mi];
    }
  }
}

// ---------------------------------------------------------------------------
// combine: merge C partials per (qb, h) -> Ob bf16.  grid (79, 4), block 256.
// ---------------------------------------------------------------------------
__global__ __launch_bounds__(256) void combine_kernel(
    const float* __restrict__ Opart, const float* __restrict__ Ml,
    unsigned short* __restrict__ Ob, int C) {
  __shared__ float wls[4][7][32];   // [wave][c -> w_c][q]; [wave][6][q] = 1/l_tot
  int t = threadIdx.x, wv = t >> 6, lane = t & 63;
  int qb = blockIdx.x * 4 + wv;
  if (qb >= NQB) return;            // per-wave LDS region, no barriers: safe
  int h = blockIdx.y;
  size_t base = (size_t)(qb * 4 + h) * C;
  if (lane < 32) {
    float M = -1e30f;
    for (int c = 0; c < C; ++c)
      M = fmaxf(M, Ml[(base + c) * 64 + lane]);
    float lt = 0.f;
    for (int c = 0; c < C; ++c) {
      float w = __expf(Ml[(base + c) * 64 + lane] - M);
      wls[wv][c][lane] = w;
      lt += Ml[(base + c) * 64 + 32 + lane] * w;
    }
    wls[wv][6][lane] = 1.f / lt;
  }
  asm volatile("" ::: "memory");
  __builtin_amdgcn_sched_barrier(0);   // same-wave DS ordering covers lanes 32..63
  const float* Op = Opart + base * 1024;
#pragma unroll
  for (int j = 0; j < 4; ++j) {
    int q = j * 8 + (lane >> 3);
    int d = (lane & 7) * 4;
    f32x4 accv = {0.f, 0.f, 0.f, 0.f};
    for (int c = 0; c < C; ++c) {
      f32x4 v = *(const f32x4*)(Op + c * 1024 + j * 256 + lane * 4);
      float w = wls[wv][c][q];
#pragma unroll
      for (int i = 0; i < 4; ++i) accv[i] = fmaf(v[i], w, accv[i]);
    }
    float linv = wls[wv][6][q];
    u16x4 o4;
#pragma unroll
    for (int i = 0; i < 4; ++i) o4[i] = f2b(accv[i] * linv);
    *(u16x4*)(Ob + (size_t)(qb * 32 + q) * 128 + h * 32 + d) = o4;
  }
}

// ---------------------------------------------------------------------------
// epi: out[dout][l] = sum_d Ob[l][d]*Wo[dout][d] + bo[dout] + skip[dout][l]
// ---------------------------------------------------------------------------
__global__ __launch_bounds__(256) void epi_kernel(
    const unsigned short* __restrict__ Ob, const unsigned short* __restrict__ Wob,
    const float* __restrict__ bo, const float* __restrict__ skip,
    float* __restrict__ out) {
  int t = threadIdx.x, wv = t >> 6, lane = t & 63, lm = lane & 15, lg = lane >> 4;
  int l0 = blockIdx.x * 64;
  const f32x4 zf = {0.f, 0.f, 0.f, 0.f};
  bf16x8 af[2][4];
#pragma unroll
  for (int mi = 0; mi < 2; ++mi)
#pragma unroll
    for (int kk = 0; kk < 4; ++kk)
      af[mi][kk] = *(const bf16x8*)(Wob + (size_t)(wv * 32 + mi * 16 + lm) * 128 + kk * 32 + lg * 8);
  f32x4 acc[2][4] = {{zf, zf, zf, zf}, {zf, zf, zf, zf}};
#pragma unroll
  for (int kk = 0; kk < 4; ++kk) {
    bf16x8 bfr[4];
#pragma unroll
    for (int ni = 0; ni < 4; ++ni)
      bfr[ni] = *(const bf16x8*)(Ob + (size_t)(l0 + ni * 16 + lm) * 128 + kk * 32 + lg * 8);
#pragma unroll
    for (int mi = 0; mi < 2; ++mi)
#pragma unroll
      for (int ni = 0; ni < 4; ++ni)
        acc[mi][ni] = __builtin_amdgcn_mfma_f32_16x16x32_bf16(af[mi][kk], bfr[ni], acc[mi][ni], 0, 0, 0);
  }
#pragma unroll
  for (int mi = 0; mi < 2; ++mi)
#pragma unroll
    for (int r = 0; r < 4; ++r) {
      int dout = wv * 32 + mi * 16 + lg * 4 + r;
      float bb = bo[dout];
#pragma unroll
      for (int ni = 0; ni < 4; ++ni) {
        int l = l0 + ni * 16 + lm;
        if (l < LQ)
          out[(size_t)dout * LQ + l] = acc[mi][ni][r] + bb + skip[(size_t)dout * LQ + l];
      }
    }
}

// ---------------------------------------------------------------------------
extern "C" void kernel_launch(void* const* d_in, const int* in_sizes, int n_in,
                              void* d_out, int out_size, void* d_ws, size_t ws_size,
                              hipStream_t stream) {
  const float* query = (const float*)d_in[0];
  const float* key   = (const float*)d_in[1];
  const float* value = (const float*)d_in[2];
  const float* depth = (const float*)d_in[3];
  const float* conf  = (const float*)d_in[4];
  const float* skip  = (const float*)d_in[5];
  const float* Wq = (const float*)d_in[6];   const float* bq = (const float*)d_in[7];
  const float* Wk = (const float*)d_in[8];   const float* bk = (const float*)d_in[9];
  const float* Wv = (const float*)d_in[10];  const float* bv = (const float*)d_in[11];
  const float* Wo = (const float*)d_in[12];  const float* bo = (const float*)d_in[13];
  const float* dw1 = (const float*)d_in[14]; const float* db1 = (const float*)d_in[15];
  const float* dw2 = (const float*)d_in[16]; const float* db2 = (const float*)d_in[17];
  float* out = (float*)d_out;
  char* ws = (char*)d_ws;

  // workspace layout (bytes)
  unsigned short* Qb   = (unsigned short*)(ws + 0);         // 10048 x 128 bf16
  unsigned short* Kb   = (unsigned short*)(ws + 2572288);   //  4224 x 128 bf16
  unsigned short* Vt   = (unsigned short*)(ws + 3653632);   //   128 x 4224 bf16
  float*          bias = (float*)        (ws + 4734976);    //     4 x 4224 f32
  unsigned short* Wqb  = (unsigned short*)(ws + 4802560);   // 128x128 bf16 each
  unsigned short* Wkb  = (unsigned short*)(ws + 4835328);
  unsigned short* Wvb  = (unsigned short*)(ws + 4868096);
  unsigned short* Wob  = (unsigned short*)(ws + 4900864);
  unsigned short* Ob   = (unsigned short*)(ws + 4933632);   // 10048 x 128 bf16
  const size_t splitOff = 7505920;                          // after Ob

  // pick largest chunk count C (divides 66) whose partials fit in ws
  int C = 1;
  {
    const int cand[4] = {6, 3, 2, 1};
    for (int i = 0; i < 4; ++i) {
      size_t need = splitOff + (size_t)NQB * 4 * cand[i] * (4096 + 256);
      if (ws_size >= need) { C = cand[i]; break; }
    }
  }
  int tpc = 66 / C;
  float* Opart = (float*)(ws + splitOff);
  float* Ml    = (float*)(ws + splitOff + (size_t)NQB * 4 * C * 4096);

  hipLaunchKernelGGL(misc_kernel, dim3(273), dim3(256), 0, stream,
                     depth, conf, dw1, db1, dw2, db2, Wq, Wk, Wv, Wo,
                     bias, Wqb, Wkb, Wvb, Wob);
  hipLaunchKernelGGL(proj_q_kernel, dim3(157), dim3(256), 0, stream,
                     query, Wqb, bq, Qb);
  hipLaunchKernelGGL(proj_kv_kernel, dim3(66, 2), dim3(256), 0, stream,
                     key, value, Wkb, bk, Wvb, bv, Kb, Vt);
  hipLaunchKernelGGL(attn_part_kernel, dim3(79, 4, C), dim3(256), 0, stream,
                     Qb, Kb, Vt, bias, Opart, Ml, tpc, C);
  hipLaunchKernelGGL(combine_kernel, dim3(79, 4), dim3(256), 0, stream,
                     Opart, Ml, Ob, C);
  hipLaunchKernelGGL(epi_kernel, dim3(157), dim3(256), 0, stream,
                     Ob, Wob, bo, skip, out);
}